// Round 8
// baseline (291.424 us; speedup 1.0000x reference)
//
#include <hip/hip_runtime.h>

#define IN_SIZE 256
#define N_NODES 1024
#define DEG 32
#define BATCH 16384
#define OUT_SIZE 16
#define COLS 4                        // batch columns per single-wave block
#define N_ROWS (IN_SIZE + N_NODES)    // 1280 activation rows (fp32 in LDS)
#define NPAIR (N_NODES / 2)           // 512 node pairs

// RNE float -> bf16
__device__ __forceinline__ unsigned short f2bf_rne(float f) {
    const unsigned u = __float_as_uint(f);
    return (unsigned short)((u + 0x7FFFu + ((u >> 16) & 1u)) >> 16);
}

// overflow-free tanh: s = e^{-2|z|}, t = sign(z)*(1-s)/(1+s)
__device__ __forceinline__ float tanh6(float z) {
    const float s = __expf(-2.0f * fabsf(z));
    const float r = __builtin_amdgcn_rcpf(1.0f + s);
    return copysignf(fmaf(-s, r, r), z);
}

// butterfly add across lane bits {0,1,2}: quad_perm(B1)=xor1, quad_perm(4E)=xor2,
// row_half_mirror(0x141) (== xor4 after quad uniformity). 8-lane-group sum.
template <int CTRL>
__device__ __forceinline__ float dpp_add(float v) {
    return v + __int_as_float(__builtin_amdgcn_mov_dpp(__float_as_int(v), CTRL, 0xF, 0xF, true));
}
// cross-half exchange within a 16-lane row: row_ror:8 (HW-proven ctrl 0x128)
__device__ __forceinline__ float dpp_ror8(float v) {
    return __int_as_float(__builtin_amdgcn_mov_dpp(__float_as_int(v), 0x128, 0xF, 0xF, true));
}

// ---------------------------------------------------------------------------
// Runtime dtype detector (unchanged).
// ---------------------------------------------------------------------------
__global__ __launch_bounds__(64) void ne_detect(const void* __restrict__ xraw,
                                                int* __restrict__ flag) {
    const unsigned short* xb = (const unsigned short*)xraw;
    const int tid = threadIdx.x;
    int plausible = 0;
    for (int k = tid; k < 2048; k += 64) {
        const float v = __uint_as_float((unsigned)xb[2 * k] << 16);
        const float a = fabsf(v);
        plausible += (a == 0.0f) || (a > 1e-3f && a < 1e3f) ? 1 : 0;
    }
    for (int off = 32; off > 0; off >>= 1) plausible += __shfl_down(plausible, off);
    if (tid == 0) *flag = (plausible >= (2048 * 9) / 10) ? 1 : 0;
}

// ---------------------------------------------------------------------------
// Packed tables, hot-loop loads all of the form table[(P<<4) + (lane&15)]:
//   pki[n*8+qq] = int4 ids[n][4qq..4qq+3]
//   pkw[n*8+qq] = float4 w  [n][4qq..4qq+3]
//   hza[n*8+qq] = float4 prefold coeffs (replicated over qq), order
//                 {c_ts1, c_to1, c_ts2, c_to2} for the rolling t registers;
//   hcc[n*8+qq] = float   in-pair coeff (odd nodes: h1; even: 0)
// Hazard window (gathers for pair Q issued before write(Q-2)): stale pairs
// Q-2, Q-1, Q -> even node 2Q needs h1..h4, odd 2Q+1 needs h1..h5:
//   h_k(n) = sum_r w[n][r]*[idx[n][r]==256+n-k], valid only if idx>=256.
//   even n: hza={h2,h1,h4,h3}, hcc=0.  odd n: hza={h2,h3,h4,h5}, hcc=h1.
// ---------------------------------------------------------------------------
__global__ __launch_bounds__(256) void ne_prep(const void* __restrict__ wraw,
                                               const int* __restrict__ idxs,
                                               int4* __restrict__ pki,
                                               float4* __restrict__ pkw,
                                               float4* __restrict__ hza,
                                               float* __restrict__ hcc,
                                               const int* __restrict__ flag) {
    const int isbf16 = *flag;                    // uniform
    const int tid = blockIdx.x * 256 + threadIdx.x;
    const int stride = gridDim.x * 256;
    const unsigned short* wb = (const unsigned short*)wraw;
    const float* wsrc = (const float*)wraw;
    for (int k = tid; k < N_NODES * 8; k += stride) {   // k = n*8 + qq
        const int n = k >> 3, qq = k & 7;
        const int e = n * DEG + qq * 4;
        pki[k] = make_int4(idxs[e], idxs[e + 1], idxs[e + 2], idxs[e + 3]);
        float w0 = isbf16 ? __uint_as_float((unsigned)wb[e + 0] << 16) : wsrc[e + 0];
        float w1 = isbf16 ? __uint_as_float((unsigned)wb[e + 1] << 16) : wsrc[e + 1];
        float w2 = isbf16 ? __uint_as_float((unsigned)wb[e + 2] << 16) : wsrc[e + 2];
        float w3 = isbf16 ? __uint_as_float((unsigned)wb[e + 3] << 16) : wsrc[e + 3];
        pkw[k] = make_float4(w0, w1, w2, w3);
    }
    for (int n = tid; n < N_NODES; n += stride) {
        float h1 = 0.f, h2 = 0.f, h3 = 0.f, h4 = 0.f, h5 = 0.f;
        for (int r = 0; r < DEG; ++r) {
            const int id = idxs[n * DEG + r];
            if (id < IN_SIZE) continue;          // input rows are never stale
            const int d = IN_SIZE + n - id;      // id == 256+n-d
            if (d < 1 || d > 5) continue;
            const float w = isbf16 ? __uint_as_float((unsigned)wb[n * DEG + r] << 16)
                                   : wsrc[n * DEG + r];
            if (d == 1) h1 += w; else if (d == 2) h2 += w; else if (d == 3) h3 += w;
            else if (d == 4) h4 += w; else h5 += w;
        }
        const float4 a = (n & 1) ? make_float4(h2, h3, h4, h5)
                                 : make_float4(h2, h1, h4, h3);
        const float hc = (n & 1) ? h1 : 0.0f;
#pragma unroll
        for (int r = 0; r < 8; ++r) { hza[n * 8 + r] = a; hcc[n * 8 + r] = hc; }
    }
}

// ---------------------------------------------------------------------------
// Decoupled node-pair pipeline, COLS=4 (20 KB LDS -> 8 single-wave blocks/CU
// = 2 waves/SIMD). lane = c*16 + h*8 + q. Step S:
//   1) reduce pair S+1 (4 FMA + 3 DPP; INDEPENDENT of t-chain -> compiler
//      weaves it into finalize(S)'s stall slots)
//   2) issue gathers pair S+2 (before write(S): stale = pairs S,S+1,S+2,
//      pre-zeroed 0.0, folded back via hza/hcc -> deterministic)
//   3) finalize pair S: z = acc + 4 prefold FMA; tanh -> ror8 -> hc-fma ->
//      tanh (the only serial chain); write both rows; roll t regs
//   4) refills (pair S+3 w, S+4 ids, S+2 hz; all dwordx4/dword, vmcnt-only)
// Single wave => in-order DS => stale reads are exactly 0; zero barriers.
// ---------------------------------------------------------------------------
__global__ __launch_bounds__(64) void ne_forward(const void* __restrict__ xraw,
                                                 const int4* __restrict__ pki,
                                                 const float4* __restrict__ pkw,
                                                 const float4* __restrict__ hza,
                                                 const float* __restrict__ hcc,
                                                 void* __restrict__ outraw,
                                                 const int* __restrict__ flag) {
    __shared__ float act[N_ROWS * COLS];         // 20480 B -> 8 blocks/CU
    const int lane = threadIdx.x;
    const int q = lane & 7;                      // fan-in quad 0..7
    const int h = (lane >> 3) & 1;               // node parity in pair
    const int c = lane >> 4;                     // batch column 0..3
    const int l15 = lane & 15;
    const int c0 = blockIdx.x * COLS;
    const int isbf16 = *flag;                    // uniform
    float* outf = (float*)outraw;
    unsigned short* outb = (unsigned short*)outraw;

    // ---- zero node rows so stale gathers read exactly 0.0 ----
    {
        float4* az = (float4*)(act + IN_SIZE * COLS);   // 1024 float4
#pragma unroll
        for (int t = 0; t < 16; ++t) az[t * 64 + lane] = make_float4(0.f, 0.f, 0.f, 0.f);
    }
    // ---- seed input rows 0..255 from raw x: lane seeds rows l15*16..+15, col c ----
    {
        const int b = c;
        if (isbf16) {
            const unsigned short* xb =
                (const unsigned short*)xraw + (size_t)(c0 + b) * IN_SIZE + l15 * 16;
#pragma unroll
            for (int t = 0; t < 2; ++t) {
                const uint4 v = *(const uint4*)(xb + t * 8);
                const int k0 = l15 * 16 + t * 8;
                act[(k0 + 0) * COLS + b] = __uint_as_float(v.x << 16);
                act[(k0 + 1) * COLS + b] = __uint_as_float(v.x & 0xFFFF0000u);
                act[(k0 + 2) * COLS + b] = __uint_as_float(v.y << 16);
                act[(k0 + 3) * COLS + b] = __uint_as_float(v.y & 0xFFFF0000u);
                act[(k0 + 4) * COLS + b] = __uint_as_float(v.z << 16);
                act[(k0 + 5) * COLS + b] = __uint_as_float(v.z & 0xFFFF0000u);
                act[(k0 + 6) * COLS + b] = __uint_as_float(v.w << 16);
                act[(k0 + 7) * COLS + b] = __uint_as_float(v.w & 0xFFFF0000u);
            }
        } else {
            const float* xs = (const float*)xraw + (size_t)(c0 + b) * IN_SIZE + l15 * 16;
#pragma unroll
            for (int t = 0; t < 4; ++t) {
                const float4 v = *(const float4*)(xs + t * 4);
                const int k0 = l15 * 16 + t * 4;
                act[(k0 + 0) * COLS + b] = v.x;
                act[(k0 + 1) * COLS + b] = v.y;
                act[(k0 + 2) * COLS + b] = v.z;
                act[(k0 + 3) * COLS + b] = v.w;
            }
        }
    }
    // single wave: in-order DS -> gathers below see the seed; no barrier

    // ---- prologue ----
    float accA, accB;
    float gA0, gA1, gA2, gA3, gB0, gB1, gB2, gB3;
    {   // pair 0: gather + reduce immediately (transient tables)
        const int4 it = pki[(0 << 4) + l15];
        const float4 wt = pkw[(0 << 4) + l15];
        const float x0 = act[it.x * COLS + c], x1 = act[it.y * COLS + c];
        const float x2 = act[it.z * COLS + c], x3 = act[it.w * COLS + c];
        float zr = x0 * wt.x; zr = fmaf(x1, wt.y, zr);
        zr = fmaf(x2, wt.z, zr); zr = fmaf(x3, wt.w, zr);
        zr = dpp_add<0xB1>(zr); zr = dpp_add<0x4E>(zr); zr = dpp_add<0x141>(zr);
        accA = zr;
    }
    {   // gathers pair 1 -> gA (consumed at step 0's reduce)
        const int4 it = pki[(1 << 4) + l15];
        gA0 = act[it.x * COLS + c]; gA1 = act[it.y * COLS + c];
        gA2 = act[it.z * COLS + c]; gA3 = act[it.w * COLS + c];
    }
    int4   idv0 = pki[(2 << 4) + l15], idv1 = pki[(3 << 4) + l15];
    float4 wv0  = pkw[(1 << 4) + l15], wv1  = pkw[(2 << 4) + l15];
    float4 hza0 = hza[(0 << 4) + l15], hza1 = hza[(1 << 4) + l15];
    float  hcc0 = hcc[(0 << 4) + l15], hcc1 = hcc[(1 << 4) + l15];
    float tsP1 = 0.f, toP1 = 0.f, tsP2 = 0.f, toP2 = 0.f;

// Step S. GC* = gathers of pair S+1 (consume), GN* = set to fill with pair
// S+2's gathers. WVV holds w(S+1); IDV ids(S+2); HZA/HCC pair S's coeffs.
// ACCc = acc(S) (finalize), ACCn <- acc(S+1).
#define PAIRSTEP(S, GC0, GC1, GC2, GC3, GN0, GN1, GN2, GN3,                            \
                 IDV, WVV, HZA, HCC, ACCc, ACCn, OUT, CLAMP)                           \
    {                                                                                  \
        /* 1) reduce pair S+1 (independent of t-chain) */                              \
        float zr = GC0 * WVV.x; zr = fmaf(GC1, WVV.y, zr);                             \
        zr = fmaf(GC2, WVV.z, zr); zr = fmaf(GC3, WVV.w, zr);                          \
        zr = dpp_add<0xB1>(zr); zr = dpp_add<0x4E>(zr); zr = dpp_add<0x141>(zr);       \
        ACCn = zr;                                                                     \
        /* 2) issue gathers pair S+2 (stale pairs S..S+2 covered by hza/hcc) */        \
        GN0 = act[IDV.x * COLS + c]; GN1 = act[IDV.y * COLS + c];                      \
        GN2 = act[IDV.z * COLS + c]; GN3 = act[IDV.w * COLS + c];                      \
        /* 3) finalize pair S */                                                       \
        float z = fmaf(HZA.x, tsP1, ACCc);                                             \
        z = fmaf(HZA.y, toP1, z);                                                      \
        z = fmaf(HZA.z, tsP2, z);                                                      \
        z = fmaf(HZA.w, toP2, z);                                                      \
        const float t1 = tanh6(z);                                                     \
        z = fmaf(HCC, dpp_ror8(t1), z);          /* even: HCC=0 -> unchanged */        \
        const float t = tanh6(z);                                                      \
        if (q == 0) {                                                                  \
            act[(IN_SIZE + 2 * (S) + h) * COLS + c] = t;                               \
            if (OUT) {                                                                 \
                const size_t o =                                                       \
                    (size_t)(2 * (S) + h - (N_NODES - OUT_SIZE)) * BATCH + c0 + c;     \
                if (isbf16) outb[o] = f2bf_rne(t); else outf[o] = t;                   \
            }                                                                          \
        }                                                                              \
        tsP2 = tsP1; toP2 = toP1; tsP1 = t; toP1 = dpp_ror8(t);                        \
        /* 4) refills: w(S+3), ids(S+4), hz(S+2) — flight 2 steps each */              \
        { const int Pw = (CLAMP) ? (((S) + 3 < NPAIR) ? (S) + 3 : NPAIR - 1) : (S) + 3;\
          const int Pn = (CLAMP) ? (((S) + 4 < NPAIR) ? (S) + 4 : NPAIR - 1) : (S) + 4;\
          const int Ph = (CLAMP) ? (((S) + 2 < NPAIR) ? (S) + 2 : NPAIR - 1) : (S) + 2;\
          WVV = pkw[(Pw << 4) + l15];                                                  \
          IDV = pki[(Pn << 4) + l15];                                                  \
          HZA = hza[(Ph << 4) + l15];                                                  \
          HCC = hcc[(Ph << 4) + l15]; }                                                \
    }

    // main loop: pairs 0..503 (nodes 0..1007) — no output, no clamp (S+4 <= 507)
#pragma unroll 1
    for (int S = 0; S < NPAIR - 8; S += 2) {
        PAIRSTEP(S,     gA0, gA1, gA2, gA3, gB0, gB1, gB2, gB3,
                 idv0, wv0, hza0, hcc0, accA, accB, 0, 0)
        PAIRSTEP(S + 1, gB0, gB1, gB2, gB3, gA0, gA1, gA2, gA3,
                 idv1, wv1, hza1, hcc1, accB, accA, 0, 0)
    }
    // epilogue: pairs 504..511 (nodes 1008..1023 — all outputs)
    {
        const int S = NPAIR - 8;                 // 504 (even -> slot parity holds)
        PAIRSTEP(S + 0, gA0, gA1, gA2, gA3, gB0, gB1, gB2, gB3,
                 idv0, wv0, hza0, hcc0, accA, accB, 1, 1)
        PAIRSTEP(S + 1, gB0, gB1, gB2, gB3, gA0, gA1, gA2, gA3,
                 idv1, wv1, hza1, hcc1, accB, accA, 1, 1)
        PAIRSTEP(S + 2, gA0, gA1, gA2, gA3, gB0, gB1, gB2, gB3,
                 idv0, wv0, hza0, hcc0, accA, accB, 1, 1)
        PAIRSTEP(S + 3, gB0, gB1, gB2, gB3, gA0, gA1, gA2, gA3,
                 idv1, wv1, hza1, hcc1, accB, accA, 1, 1)
        PAIRSTEP(S + 4, gA0, gA1, gA2, gA3, gB0, gB1, gB2, gB3,
                 idv0, wv0, hza0, hcc0, accA, accB, 1, 1)
        PAIRSTEP(S + 5, gB0, gB1, gB2, gB3, gA0, gA1, gA2, gA3,
                 idv1, wv1, hza1, hcc1, accB, accA, 1, 1)
        PAIRSTEP(S + 6, gA0, gA1, gA2, gA3, gB0, gB1, gB2, gB3,
                 idv0, wv0, hza0, hcc0, accA, accB, 1, 1)
        PAIRSTEP(S + 7, gB0, gB1, gB2, gB3, gA0, gA1, gA2, gA3,
                 idv1, wv1, hza1, hcc1, accB, accA, 1, 1)
    }
#undef PAIRSTEP
}

extern "C" void kernel_launch(void* const* d_in, const int* in_sizes, int n_in,
                              void* d_out, int out_size, void* d_ws, size_t ws_size,
                              hipStream_t stream) {
    const void* x   = d_in[0];                   // [BATCH][IN_SIZE]
    const void* w   = d_in[1];                   // [N_NODES][DEG]
    const int* idxs = (const int*)d_in[2];       // [N_NODES][DEG]

    int4*   pki = (int4*)d_ws;                                           // 128 KB
    float4* pkw = (float4*)((char*)d_ws + (size_t)128 * 1024);           // 128 KB
    float4* hza = (float4*)((char*)d_ws + (size_t)256 * 1024);           // 128 KB
    float*  hcc = (float*)((char*)d_ws + (size_t)384 * 1024);            // 32 KB
    int* flag   = (int*)((char*)d_ws + ((ws_size - 16) & ~(size_t)15));

    ne_detect<<<1, 64, 0, stream>>>(x, flag);
    ne_prep<<<32, 256, 0, stream>>>(w, idxs, pki, pkw, hza, hcc, flag);

    // 4096 single-wave blocks, 20 KB LDS -> 8 blocks/CU (2 waves/SIMD),
    // 2 scheduling rounds, zero barriers.
    ne_forward<<<dim3(BATCH / COLS), dim3(64), 0, stream>>>(x, pki, pkw, hza, hcc,
                                                            d_out, flag);
}